// Round 2
// baseline (454.139 us; speedup 1.0000x reference)
//
#include <hip/hip_runtime.h>
#include <math.h>

typedef unsigned short u16;
typedef __attribute__((ext_vector_type(8))) short frag8;   // 8 bf16 = 4 VGPR
typedef __attribute__((ext_vector_type(4))) float f32x4;   // MFMA acc

__device__ __forceinline__ float eluf(float v) { return v > 0.f ? v : expm1f(v); }
__device__ __forceinline__ float geluf(float v) {
  return 0.5f * v * (1.f + erff(v * 0.70710678118654752f));
}
__device__ __forceinline__ u16 f2bf(float f) {
  union { float f; unsigned int i; } v; v.f = f;
  return (u16)((v.i + 0x7fffu + ((v.i >> 16) & 1u)) >> 16);
}

#define BN_S 0.99999500003749969f   /* 1/sqrt(1+1e-5) */

// ============================================================
// k_tws1
// ============================================================
__global__ void k_tws1(const float* tw1, const float* tw2, const float* tw3, const float* tw4,
                       const float* tb1, const float* tb2, const float* tb3, const float* tb4,
                       const float* bn1g, const float* bn1b,
                       float* tws1, float* c1) {
  int idx = blockIdx.x * 256 + threadIdx.x;
  if (idx < 8320) {
    int i = idx / 65, u = idx - i * 65;
    int g = i >> 5, il = i & 31;
    const float* tws[4] = {tw1, tw2, tw3, tw4};
    const int P[4] = {7, 12, 25, 32};
    int c = u - 32;
    float s1 = bn1g[i] * BN_S;
    float val = 0.f;
    int p = P[g];
    if (c >= -p && c <= p) val = s1 * tws[g][il * (2 * p + 1) + (c + p)];
    tws1[idx] = val;
  } else if (idx < 8448) {
    int i = idx - 8320;
    int g = i >> 5, il = i & 31;
    const float* tbs[4] = {tb1, tb2, tb3, tb4};
    float s1 = bn1g[i] * BN_S;
    c1[i] = s1 * tbs[g][il] + bn1b[i];
  }
}

// ============================================================
// k_weff
// ============================================================
__global__ __launch_bounds__(256) void k_weff(const float* __restrict__ sw, const float* __restrict__ sb,
                                              const float* __restrict__ tws1, const float* __restrict__ c1,
                                              u16* __restrict__ Wb, float* __restrict__ biasEff) {
  const int lane = threadIdx.x & 63, wave = threadIdx.x >> 6;
  const int u = blockIdx.x;
  const int o = blockIdx.y * 4 + wave;
  const float* swp = sw + o * 8192 + lane;     // + i*64
  if (u < 65) {
    const float* tp = tws1 + u;                // + i*65 (wave-uniform)
    float a0 = 0.f, a1 = 0.f, a2 = 0.f, a3 = 0.f;
    #pragma unroll 8
    for (int i = 0; i < 128; i += 4) {
      a0 = fmaf(swp[(i + 0) * 64], tp[(i + 0) * 65], a0);
      a1 = fmaf(swp[(i + 1) * 64], tp[(i + 1) * 65], a1);
      a2 = fmaf(swp[(i + 2) * 64], tp[(i + 2) * 65], a2);
      a3 = fmaf(swp[(i + 3) * 64], tp[(i + 3) * 65], a3);
    }
    Wb[(u * 128 + o) * 64 + lane] = f2bf((a0 + a1) + (a2 + a3));
  } else {
    float pa = 0.f;
    #pragma unroll 8
    for (int i = 0; i < 128; i++)
      pa = fmaf(swp[i * 64], c1[i], pa);
    #pragma unroll
    for (int off = 32; off; off >>= 1) pa += __shfl_xor(pa, off);
    if (lane == 0) biasEff[o] = pa + sb[o];
  }
}

// ============================================================
// k_conv (MFMA): o-tile now 32 (grid (16,4,16)=1024 blocks -> 2x occupancy).
// Per-output math identical to previous version (bit-identical).
// ============================================================
__global__ __launch_bounds__(256) void k_conv(const float* __restrict__ x,
                                              const u16* __restrict__ Wb,
                                              const float* __restrict__ biasEff,
                                              const float* __restrict__ bn2g, const float* __restrict__ bn2b,
                                              float* __restrict__ z) {
  __shared__ u16 xs[128 * 88];   // 22.5 KB; row tt -> t0-32+tt, col kh
  const int tid = threadIdx.x;
  const int t0 = blockIdx.x * 64;
  const int o0 = blockIdx.y * 32;
  const int b  = blockIdx.z;

  #pragma unroll
  for (int i = 0; i < 8; i++) {
    int pos = tid + i * 256;
    int kh = pos >> 5;
    int tt = (pos & 31) * 4;
    int gt = t0 - 32 + tt;
    const float* xp = x + (b * 64 + kh) * 1000;
    float v[4];
    if (gt >= 0 && gt + 3 < 1000) {
      float4 f = *(const float4*)(xp + gt);
      v[0] = f.x; v[1] = f.y; v[2] = f.z; v[3] = f.w;
    } else {
      #pragma unroll
      for (int e = 0; e < 4; e++) { int g2 = gt + e; v[e] = (g2 >= 0 && g2 < 1000) ? xp[g2] : 0.f; }
    }
    #pragma unroll
    for (int e = 0; e < 4; e++) xs[(tt + e) * 88 + kh] = f2bf(v[e]);
  }
  __syncthreads();

  const int lane = tid & 63, wave = tid >> 6;
  const int wt = (wave & 1) * 32;
  const int wo = (wave >> 1) * 16;
  const int m = lane & 15, q = lane >> 4;

  f32x4 acc[2];
  #pragma unroll
  for (int i = 0; i < 2; i++) acc[i] = (f32x4){0.f, 0.f, 0.f, 0.f};

  #pragma unroll 2
  for (int u = 0; u < 65; u++) {
    frag8 A[2][2], B[2];
    #pragma unroll
    for (int tp = 0; tp < 2; tp++)
      #pragma unroll
      for (int kc = 0; kc < 2; kc++)
        A[tp][kc] = *(const frag8*)&xs[(wt + tp * 16 + m + u) * 88 + kc * 32 + q * 8];
    #pragma unroll
    for (int kc = 0; kc < 2; kc++)
      B[kc] = *(const frag8*)(Wb + ((u * 128) + o0 + wo + m) * 64 + kc * 32 + q * 8);
    #pragma unroll
    for (int tp = 0; tp < 2; tp++) {
      acc[tp] = __builtin_amdgcn_mfma_f32_16x16x32_bf16(A[tp][0], B[0], acc[tp], 0, 0, 0);
      acc[tp] = __builtin_amdgcn_mfma_f32_16x16x32_bf16(A[tp][1], B[1], acc[tp], 0, 0, 0);
    }
  }

  {
    int o = o0 + wo + m;
    float s2 = bn2g[o] * BN_S;
    float be = biasEff[o], b2 = bn2b[o];
    #pragma unroll
    for (int tp = 0; tp < 2; tp++) {
      #pragma unroll
      for (int r = 0; r < 4; r++) {
        int t = t0 + wt + tp * 16 + q * 4 + r;
        if (t < 1000)
          z[(b * 128 + o) * 1000 + t] = eluf((acc[tp][r] + be) * s2 + b2);
      }
    }
  }
}

// ============================================================
// k_pool
// ============================================================
__global__ __launch_bounds__(128) void k_pool(const float* __restrict__ z, float* __restrict__ X) {
  int p = blockIdx.x, b = blockIdx.y, o = threadIdx.x;
  const float* zp = z + (b * 128 + o) * 1000 + p * 15;
  float s = 0.f, ss = 0.f;
  #pragma unroll
  for (int k = 0; k < 50; k++) { float v = zp[k]; s += v; ss = fmaf(v, v, ss); }
  float m = s * 0.02f;
  float var = (ss - s * m) * (1.f / 49.f);
  var = fminf(fmaxf(var, 1e-6f), 1e6f);
  X[(b * 64 + p) * 128 + o] = m;
  X[((16 + b) * 64 + p) * 128 + o] = logf(var);
}

// ============================================================
// k_cvt6: encoder weights f32 -> bf16
// ============================================================
__global__ __launch_bounds__(256) void k_cvt6(const float* __restrict__ wq, const float* __restrict__ wk,
                                              const float* __restrict__ wv, const float* __restrict__ wo,
                                              const float* __restrict__ f1w, const float* __restrict__ f2w,
                                              u16* __restrict__ out) {
  int i = blockIdx.x * 256 + threadIdx.x;   // float4 index, total 196608
  if (i >= 196608) return;
  int fi = i * 4;
  const float* src; int off;
  if      (fi < 65536)  { src = wq;  off = fi; }
  else if (fi < 131072) { src = wk;  off = fi - 65536; }
  else if (fi < 196608) { src = wv;  off = fi - 131072; }
  else if (fi < 262144) { src = wo;  off = fi - 196608; }
  else if (fi < 524288) { src = f1w; off = fi - 262144; }
  else                  { src = f2w; off = fi - 524288; }
  float4 v = *(const float4*)(src + off);
  ushort4 p;
  p.x = f2bf(v.x); p.y = f2bf(v.y); p.z = f2bf(v.z); p.w = f2bf(v.w);
  *(ushort4*)(out + fi) = p;
}

// ============================================================
// k_enc: fused 4-layer encoder. 32 blocks x 1024 threads (16 waves).
// Work per phase split across 16 waves; attention on waves 0-7
// (identical summation order to previous version -> bit-identical).
//   LDS: Xs f32[64][132] + Hs/AOs bf16[64][136] + QKV f32[3][64][132]
//        (F1s double-buffer aliases QKV) = 152.6 KB
// ============================================================
__device__ __forceinline__ void ln128(const float* __restrict__ Xs, u16* __restrict__ Hs,
                                      const float* __restrict__ g, const float* __restrict__ b,
                                      int lane, int wave) {
  float g0 = g[lane], g1 = g[64 + lane], b0 = b[lane], b1 = b[64 + lane];
  #pragma unroll 1
  for (int rr = 0; rr < 4; rr++) {
    int r = wave * 4 + rr;
    float v0 = Xs[r * 132 + lane], v1 = Xs[r * 132 + 64 + lane];
    float s_ = v0 + v1;
    #pragma unroll
    for (int off = 32; off; off >>= 1) s_ += __shfl_xor(s_, off);
    float mn = s_ * (1.f / 128.f);
    float d0 = v0 - mn, d1 = v1 - mn;
    float qq = d0 * d0 + d1 * d1;
    #pragma unroll
    for (int off = 32; off; off >>= 1) qq += __shfl_xor(qq, off);
    float rs = rsqrtf(qq * (1.f / 128.f) + 1e-5f);
    Hs[r * 136 + lane]      = f2bf(d0 * rs * g0 + b0);
    Hs[r * 136 + 64 + lane] = f2bf(d1 * rs * g1 + b1);
  }
}

__global__ __launch_bounds__(1024, 1) void k_enc(float* __restrict__ X,
                                                 const u16* __restrict__ Wenc,
                                                 const float* __restrict__ ln1g, const float* __restrict__ ln1b,
                                                 const float* __restrict__ ln2g, const float* __restrict__ ln2b,
                                                 const float* __restrict__ bq, const float* __restrict__ bk,
                                                 const float* __restrict__ bv, const float* __restrict__ bo,
                                                 const float* __restrict__ f1b, const float* __restrict__ f2b) {
  __shared__ float Xs[64 * 132];
  __shared__ u16   Hs[64 * 136];     // LN out / AOs (attn out) / LN2 out
  __shared__ float QKV[3 * 64 * 132];
  float* Qs = QKV;
  float* Ks = QKV + 64 * 132;
  float* Vs = QKV + 2 * 64 * 132;
  u16* AOs = Hs;                      // attn output lives in Hs region
  u16* F1a = (u16*)QKV;               // FF double buffers alias QKV (dead then)
  u16* F1b_ = (u16*)QKV + 64 * 136;

  const int tid = threadIdx.x;
  const int lane = tid & 63, wave = tid >> 6;   // wave 0..15
  const int m = lane & 15, q = lane >> 4;
  float* Xg = X + blockIdx.x * 64 * 128;

  const u16* WQ  = Wenc;
  const u16* WK  = Wenc + 65536;
  const u16* WV  = Wenc + 131072;
  const u16* WO  = Wenc + 196608;
  const u16* F1W = Wenc + 262144;
  const u16* F2W = Wenc + 524288;

  for (int i = tid; i < 8192; i += 1024) Xs[(i >> 7) * 132 + (i & 127)] = Xg[i];
  __syncthreads();

  #pragma unroll 1
  for (int l = 0; l < 4; l++) {
    const u16* wqb  = WQ  + l * 16384;
    const u16* wkb  = WK  + l * 16384;
    const u16* wvb  = WV  + l * 16384;
    const u16* wob  = WO  + l * 16384;
    const u16* f1wb = F1W + l * 65536;
    const u16* f2wb = F2W + l * 65536;

    // ---- LN1 -> Hs ----
    ln128(Xs, Hs, ln1g + l * 128, ln1b + l * 128, lane, wave);
    __syncthreads();

    // ---- QKV: 48 units = (ns 0..23) x (mh 0..1); wave does 3 units ----
    #pragma unroll
    for (int s = 0; s < 3; s++) {
      int uidx = wave * 3 + s;
      int ns = uidx >> 1, mh = uidx & 1;
      int which = ns >> 3, nsl = ns & 7;
      const u16* Bp = (which == 0 ? wqb : which == 1 ? wkb : wvb) + (nsl * 16) * 128;
      float* Dst = (which == 0 ? Qs : which == 1 ? Ks : Vs);
      const float* bptr = (which == 0 ? bq : which == 1 ? bk : bv) + l * 128;
      f32x4 a2[2];
      a2[0] = (f32x4){0,0,0,0}; a2[1] = (f32x4){0,0,0,0};
      #pragma unroll
      for (int kc = 0; kc < 4; kc++) {
        frag8 Bf = *(const frag8*)(Bp + m * 128 + kc * 32 + q * 8);
        #pragma unroll
        for (int t = 0; t < 2; t++) {
          frag8 Af = *(const frag8*)&Hs[(mh * 32 + t * 16 + m) * 136 + kc * 32 + q * 8];
          a2[t] = __builtin_amdgcn_mfma_f32_16x16x32_bf16(Af, Bf, a2[t], 0, 0, 0);
        }
      }
      float bvv = bptr[nsl * 16 + m];
      #pragma unroll
      for (int t = 0; t < 2; t++)
        #pragma unroll
        for (int r = 0; r < 4; r++)
          Dst[(mh * 32 + t * 16 + q * 4 + r) * 132 + nsl * 16 + m] = a2[t][r] + bvv;
    }
    __syncthreads();

    // ---- attention: waves 0-7 (wave=head, lane=query row), 8-15 idle ----
    if (wave < 8) {
      const int h = wave, qr = lane;
      float qv[16];
      {
        const float4* qp = (const float4*)(Qs + qr * 132 + h * 16);
        #pragma unroll
        for (int j = 0; j < 4; j++) {
          float4 t = qp[j];
          qv[j * 4 + 0] = t.x; qv[j * 4 + 1] = t.y; qv[j * 4 + 2] = t.z; qv[j * 4 + 3] = t.w;
        }
      }
      const float* kbase = Ks + h * 16;
      const float* vbase = Vs + h * 16;
      float mrun = -1e30f, lrun = 0.f;
      float o[16];
      #pragma unroll
      for (int j = 0; j < 16; j++) o[j] = 0.f;
      #pragma unroll 1
      for (int k = 0; k < 64; k++) {
        const float4* kp = (const float4*)(kbase + k * 132);
        float4 k0 = kp[0], k1 = kp[1], k2 = kp[2], k3 = kp[3];
        float s0 = qv[0] * k0.x + qv[1] * k0.y + qv[2] * k0.z + qv[3] * k0.w;
        float s1 = qv[4] * k1.x + qv[5] * k1.y + qv[6] * k1.z + qv[7] * k1.w;
        float s2 = qv[8] * k2.x + qv[9] * k2.y + qv[10] * k2.z + qv[11] * k2.w;
        float s3 = qv[12] * k3.x + qv[13] * k3.y + qv[14] * k3.z + qv[15] * k3.w;
        float sc = ((s0 + s1) + (s2 + s3)) * 0.25f;
        float mn = fmaxf(mrun, sc);
        float corr = __expf(mrun - mn);
        float p = __expf(sc - mn);
        lrun = fmaf(lrun, corr, p);
        const float4* vp = (const float4*)(vbase + k * 132);
        float4 v0 = vp[0], v1 = vp[1], v2 = vp[2], v3 = vp[3];
        o[0]  = fmaf(o[0],  corr, p * v0.x); o[1]  = fmaf(o[1],  corr, p * v0.y);
        o[2]  = fmaf(o[2],  corr, p * v0.z); o[3]  = fmaf(o[3],  corr, p * v0.w);
        o[4]  = fmaf(o[4],  corr, p * v1.x); o[5]  = fmaf(o[5],  corr, p * v1.y);
        o[6]  = fmaf(o[6],  corr, p * v1.z); o[7]  = fmaf(o[7],  corr, p * v1.w);
        o[8]  = fmaf(o[8],  corr, p * v2.x); o[9]  = fmaf(o[9],  corr, p * v2.y);
        o[10] = fmaf(o[10], corr, p * v2.z); o[11] = fmaf(o[11], corr, p * v2.w);
        o[12] = fmaf(o[12], corr, p * v3.x); o[13] = fmaf(o[13], corr, p * v3.y);
        o[14] = fmaf(o[14], corr, p * v3.z); o[15] = fmaf(o[15], corr, p * v3.w);
        mrun = mn;
      }
      float inv = 1.f / lrun;
      u16* aop = AOs + qr * 136 + h * 16;
      #pragma unroll
      for (int j = 0; j < 16; j++) aop[j] = f2bf(o[j] * inv);
    }
    __syncthreads();

    // ---- O-proj + residual: 16 units = (ns 0..7) x (mh 0..1) ----
    {
      int ns = wave >> 1, mh = wave & 1;
      const u16* Bp = wob + (ns * 16) * 128;
      f32x4 a2[2];
      a2[0] = (f32x4){0,0,0,0}; a2[1] = (f32x4){0,0,0,0};
      #pragma unroll
      for (int kc = 0; kc < 4; kc++) {
        frag8 Bf = *(const frag8*)(Bp + m * 128 + kc * 32 + q * 8);
        #pragma unroll
        for (int t = 0; t < 2; t++) {
          frag8 Af = *(const frag8*)&AOs[(mh * 32 + t * 16 + m) * 136 + kc * 32 + q * 8];
          a2[t] = __builtin_amdgcn_mfma_f32_16x16x32_bf16(Af, Bf, a2[t], 0, 0, 0);
        }
      }
      float bvv = bo[l * 128 + ns * 16 + m];
      #pragma unroll
      for (int t = 0; t < 2; t++)
        #pragma unroll
        for (int r = 0; r < 4; r++)
          Xs[(mh * 32 + t * 16 + q * 4 + r) * 132 + ns * 16 + m] += a2[t][r] + bvv;
    }
    __syncthreads();

    // ---- LN2 -> Hs ----
    ln128(Xs, Hs, ln2g + l * 128, ln2b + l * 128, lane, wave);
    __syncthreads();

    // ---- FF: 4 chunks of 128 F1-cols; F1 double-buffered in LDS ----
    {
      int ns = wave >> 1, mh = wave & 1;
      f32x4 acc2[2];
      acc2[0] = (f32x4){0,0,0,0}; acc2[1] = (f32x4){0,0,0,0};
      #pragma unroll 1
      for (int c = 0; c < 4; c++) {
        u16* F1c = (c & 1) ? F1b_ : F1a;
        // FF1 unit: cols c*128 + ns*16
        {
          const u16* Bp = f1wb + (c * 128 + ns * 16) * 128;
          f32x4 a1[2];
          a1[0] = (f32x4){0,0,0,0}; a1[1] = (f32x4){0,0,0,0};
          #pragma unroll
          for (int kc = 0; kc < 4; kc++) {
            frag8 Bf = *(const frag8*)(Bp + m * 128 + kc * 32 + q * 8);
            #pragma unroll
            for (int t = 0; t < 2; t++) {
              frag8 Af = *(const frag8*)&Hs[(mh * 32 + t * 16 + m) * 136 + kc * 32 + q * 8];
              a1[t] = __builtin_amdgcn_mfma_f32_16x16x32_bf16(Af, Bf, a1[t], 0, 0, 0);
            }
          }
          float b1v = f1b[l * 512 + c * 128 + ns * 16 + m];
          #pragma unroll
          for (int t = 0; t < 2; t++)
            #pragma unroll
            for (int r = 0; r < 4; r++)
              F1c[(mh * 32 + t * 16 + q * 4 + r) * 136 + ns * 16 + m] = f2bf(geluf(a1[t][r] + b1v));
        }
        __syncthreads();
        // FF2 partial over this chunk's K-slice
        {
          const u16* Bp = f2wb + (ns * 16) * 512 + c * 128;
          #pragma unroll
          for (int kc = 0; kc < 4; kc++) {
            frag8 Bf = *(const frag8*)(Bp + m * 512 + kc * 32 + q * 8);
            #pragma unroll
            for (int t = 0; t < 2; t++) {
              frag8 Af = *(const frag8*)&F1c[(mh * 32 + t * 16 + m) * 136 + kc * 32 + q * 8];
              acc2[t] = __builtin_amdgcn_mfma_f32_16x16x32_bf16(Af, Bf, acc2[t], 0, 0, 0);
            }
          }
        }
        // no barrier: next chunk writes the other buffer
      }
      float b2v = f2b[l * 128 + ns * 16 + m];
      #pragma unroll
      for (int t = 0; t < 2; t++)
        #pragma unroll
        for (int r = 0; r < 4; r++)
          Xs[(mh * 32 + t * 16 + q * 4 + r) * 132 + ns * 16 + m] += acc2[t][r] + b2v;
    }
    __syncthreads();
  }

  for (int i = tid; i < 8192; i += 1024) Xg[i] = Xs[(i >> 7) * 132 + (i & 127)];
}

// ============================================================
// k_head1
// ============================================================
__global__ __launch_bounds__(256) void k_head1(const float* __restrict__ X, const float* __restrict__ ew,
                                               const float* __restrict__ eb, const float* __restrict__ g3,
                                               const float* __restrict__ b3, float* __restrict__ G) {
  __shared__ float Xs[2][8192];   // 64 KB
  int b = blockIdx.x, ot = blockIdx.y;
  int tid = threadIdx.x;
  {
    const float4* x1 = (const float4*)(X + b * 8192);
    const float4* x2 = (const float4*)(X + (16 + b) * 8192);
    float4* s1 = (float4*)&Xs[0][0];
    float4* s2 = (float4*)&Xs[1][0];
    for (int i = tid; i < 2048; i += 256) { s1[i] = x1[i]; s2[i] = x2[i]; }
  }
  __syncthreads();
  int w = tid & 127, og = tid >> 7;
  int oc0 = ot * 16 + og * 8;
  float a[8] = {};
  for (int ic = 0; ic < 64; ic++) {
    float x1v = Xs[0][ic * 128 + w], x2v = Xs[1][ic * 128 + w];
    #pragma unroll
    for (int j = 0; j < 8; j++) {
      a[j] = fmaf(ew[((oc0 + j) * 64 + ic) * 2 + 0], x1v, a[j]);
      a[j] = fmaf(ew[((oc0 + j) * 64 + ic) * 2 + 1], x2v, a[j]);
    }
  }
  #pragma unroll
  for (int j = 0; j < 8; j++) {
    int oc = oc0 + j;
    float v = (a[j] + eb[oc]) * (g3[oc] * BN_S) + b3[oc];
    G[(b * 64 + oc) * 128 + w] = eluf(v);
  }
}

// ============================================================
// k_head2
// ============================================================
__global__ __launch_bounds__(256) void k_head2(const float* __restrict__ G, const float* __restrict__ cw,
                                               const float* __restrict__ cb, float* __restrict__ out) {
  __shared__ float red[256];
  int b = blockIdx.x, c = blockIdx.y, tid = threadIdx.x;
  const float4* g4 = (const float4*)(G + b * 8192);
  const float4* c4 = (const float4*)(cw + c * 8192);
  float p = 0.f;
  for (int i = tid; i < 2048; i += 256) {
    float4 g = g4[i], w = c4[i];
    p += g.x * w.x + g.y * w.y + g.z * w.z + g.w * w.w;
  }
  red[tid] = p;
  __syncthreads();
  for (int s = 128; s > 0; s >>= 1) {
    if (tid < s) red[tid] += red[tid + s];
    __syncthreads();
  }
  if (tid == 0) out[b * 4 + c] = red[0] + cb[c];
}

// ============================================================
extern "C" void kernel_launch(void* const* d_in, const int* in_sizes, int n_in,
                              void* d_out, int out_size, void* d_ws, size_t ws_size,
                              hipStream_t stream) {
  const float* x    = (const float*)d_in[0];
  const float* tw1  = (const float*)d_in[1];  const float* tb1 = (const float*)d_in[2];
  const float* tw2  = (const float*)d_in[3];  const float* tb2 = (const float*)d_in[4];
  const float* tw3  = (const float*)d_in[5];  const float* tb3 = (const float*)d_in[6];
  const float* tw4  = (const float*)d_in[7];  const float* tb4 = (const float*)d_in[8];
  const float* bn1g = (const float*)d_in[9];  const float* bn1b = (const float*)d_in[10];
  const float* sw   = (const float*)d_in[11]; const float* sb   = (const float*)d_in[12];
  const float* bn2g = (const float*)d_in[13]; const float* bn2b = (const float*)d_in[14];
  const float* ln1g = (const float*)d_in[15]; const float* ln1b = (const float*)d_in[16];
  const float* ln2g = (const float*)d_in[17]; const float* ln2b = (const float*)d_in[18];
  const float* wq   = (const float*)d_in[19]; const float* bq   = (const float*)d_in[20];
  const float* wk   = (const float*)d_in[21]; const float* bk   = (const float*)d_in[22];
  const float* wv   = (const float*)d_in[23]; const float* bv   = (const float*)d_in[24];
  const float* wo   = (const float*)d_in[25]; const float* bo   = (const float*)d_in[26];
  const float* f1w  = (const float*)d_in[27]; const float* f1b  = (const float*)d_in[28];
  const float* f2w  = (const float*)d_in[29]; const float* f2b  = (const float*)d_in[30];
  const float* ew   = (const float*)d_in[31]; const float* eb   = (const float*)d_in[32];
  const float* g3   = (const float*)d_in[33]; const float* b3   = (const float*)d_in[34];
  const float* cw   = (const float*)d_in[35]; const float* cb   = (const float*)d_in[36];

  float* ws      = (float*)d_ws;
  float* tws1    = ws;               // 8320
  float* c1      = ws + 8320;        // 128
  float* biasEff = ws + 8448;        // 128
  u16*   Wb      = (u16*)(ws + 8576);// 532480 bf16 [u][o][kh] (1.04 MB)
  float* z       = ws + 541056;      // 2048000 [b][o][t]; reused as G after pool
  float* X       = ws + 2589056;     // 262144  [2048][128]
  u16*   Wenc    = (u16*)(ws + 3113344); // 786432 bf16 encoder weights (1.5 MB)
  float* G       = z;                // 131072 (z dead after k_pool)

  k_cvt6<<<768, 256, 0, stream>>>(wq, wk, wv, wo, f1w, f2w, Wenc);
  k_tws1<<<33, 256, 0, stream>>>(tw1, tw2, tw3, tw4, tb1, tb2, tb3, tb4, bn1g, bn1b, tws1, c1);
  k_weff<<<dim3(66, 32), 256, 0, stream>>>(sw, sb, tws1, c1, Wb, biasEff);
  k_conv<<<dim3(16, 4, 16), 256, 0, stream>>>(x, Wb, biasEff, bn2g, bn2b, z);
  k_pool<<<dim3(64, 16), 128, 0, stream>>>(z, X);

  k_enc<<<32, 1024, 0, stream>>>(X, Wenc, ln1g, ln1b, ln2g, ln2b, bq, bk, bv, bo, f1b, f2b);

  k_head1<<<dim3(16, 4), 256, 0, stream>>>(X, ew, eb, g3, b3, G);
  k_head2<<<dim3(16, 4), 256, 0, stream>>>(G, cw, cb, (float*)d_out);
}

// Round 3
// 404.760 us; speedup vs baseline: 1.1220x; 1.1220x over previous
//
#include <hip/hip_runtime.h>
#include <math.h>

typedef unsigned short u16;
typedef __attribute__((ext_vector_type(8))) short frag8;   // 8 bf16 = 4 VGPR
typedef __attribute__((ext_vector_type(4))) float f32x4;   // MFMA acc

__device__ __forceinline__ float eluf(float v) { return v > 0.f ? v : expm1f(v); }
__device__ __forceinline__ float geluf(float v) {
  return 0.5f * v * (1.f + erff(v * 0.70710678118654752f));
}
__device__ __forceinline__ u16 f2bf(float f) {
  union { float f; unsigned int i; } v; v.f = f;
  return (u16)((v.i + 0x7fffu + ((v.i >> 16) & 1u)) >> 16);
}

#define BN_S 0.99999500003749969f   /* 1/sqrt(1+1e-5) */

// ============================================================
// k_tws1
// ============================================================
__global__ void k_tws1(const float* tw1, const float* tw2, const float* tw3, const float* tw4,
                       const float* tb1, const float* tb2, const float* tb3, const float* tb4,
                       const float* bn1g, const float* bn1b,
                       float* tws1, float* c1) {
  int idx = blockIdx.x * 256 + threadIdx.x;
  if (idx < 8320) {
    int i = idx / 65, u = idx - i * 65;
    int g = i >> 5, il = i & 31;
    const float* tws[4] = {tw1, tw2, tw3, tw4};
    const int P[4] = {7, 12, 25, 32};
    int c = u - 32;
    float s1 = bn1g[i] * BN_S;
    float val = 0.f;
    int p = P[g];
    if (c >= -p && c <= p) val = s1 * tws[g][il * (2 * p + 1) + (c + p)];
    tws1[idx] = val;
  } else if (idx < 8448) {
    int i = idx - 8320;
    int g = i >> 5, il = i & 31;
    const float* tbs[4] = {tb1, tb2, tb3, tb4};
    float s1 = bn1g[i] * BN_S;
    c1[i] = s1 * tbs[g][il] + bn1b[i];
  }
}

// ============================================================
// k_weff: one block per o (128 blocks). sw[o] (32KB) + tws1 (33KB) staged
// in LDS once; each wave computes 16-17 u columns. Accumulation pattern
// identical to previous version (4 partials by i mod 4) -> bit-identical Wb.
// ============================================================
__global__ __launch_bounds__(256) void k_weff(const float* __restrict__ sw, const float* __restrict__ sb,
                                              const float* __restrict__ tws1, const float* __restrict__ c1,
                                              u16* __restrict__ Wb, float* __restrict__ biasEff) {
  __shared__ float swl[8192];   // [i][kh]
  __shared__ float tl[8320];    // [i][u]
  const int tid = threadIdx.x, lane = tid & 63, wave = tid >> 6;
  const int o = blockIdx.x;
  for (int idx = tid; idx < 8192; idx += 256) swl[idx] = sw[o * 8192 + idx];
  for (int idx = tid; idx < 8320; idx += 256) tl[idx] = tws1[idx];
  __syncthreads();

  #pragma unroll 1
  for (int j = 0; j < 4; j++) {
    int u0 = (wave + 4 * j) * 4;     // 4 consecutive u, u0 in {0,4,...,60}
    float a[4][4];
    #pragma unroll
    for (int uu = 0; uu < 4; uu++)
      #pragma unroll
      for (int r = 0; r < 4; r++) a[uu][r] = 0.f;
    #pragma unroll 1
    for (int i = 0; i < 128; i += 4) {
      #pragma unroll
      for (int ii = 0; ii < 4; ii++) {
        float s = swl[(i + ii) * 64 + lane];
        #pragma unroll
        for (int uu = 0; uu < 4; uu++)
          a[uu][ii] = fmaf(s, tl[(i + ii) * 65 + u0 + uu], a[uu][ii]);
      }
    }
    #pragma unroll
    for (int uu = 0; uu < 4; uu++)
      Wb[((u0 + uu) * 128 + o) * 64 + lane] = f2bf((a[uu][0] + a[uu][1]) + (a[uu][2] + a[uu][3]));
  }

  if (wave == 0) {   // u = 64
    float a[4] = {0.f, 0.f, 0.f, 0.f};
    #pragma unroll 1
    for (int i = 0; i < 128; i += 4) {
      #pragma unroll
      for (int ii = 0; ii < 4; ii++)
        a[ii] = fmaf(swl[(i + ii) * 64 + lane], tl[(i + ii) * 65 + 64], a[ii]);
    }
    Wb[(64 * 128 + o) * 64 + lane] = f2bf((a[0] + a[1]) + (a[2] + a[3]));
  } else if (wave == 1) {   // biasEff[o]
    float pa = 0.f;
    #pragma unroll 8
    for (int i = 0; i < 128; i++)
      pa = fmaf(swl[i * 64 + lane], c1[i], pa);
    #pragma unroll
    for (int off = 32; off; off >>= 1) pa += __shfl_xor(pa, off);
    if (lane == 0) biasEff[o] = pa + sb[o];
  }
}

// ============================================================
// k_conv (MFMA): o-tile 32, grid (16,4,16).
// ============================================================
__global__ __launch_bounds__(256) void k_conv(const float* __restrict__ x,
                                              const u16* __restrict__ Wb,
                                              const float* __restrict__ biasEff,
                                              const float* __restrict__ bn2g, const float* __restrict__ bn2b,
                                              float* __restrict__ z) {
  __shared__ u16 xs[128 * 88];   // 22.5 KB; row tt -> t0-32+tt, col kh
  const int tid = threadIdx.x;
  const int t0 = blockIdx.x * 64;
  const int o0 = blockIdx.y * 32;
  const int b  = blockIdx.z;

  #pragma unroll
  for (int i = 0; i < 8; i++) {
    int pos = tid + i * 256;
    int kh = pos >> 5;
    int tt = (pos & 31) * 4;
    int gt = t0 - 32 + tt;
    const float* xp = x + (b * 64 + kh) * 1000;
    float v[4];
    if (gt >= 0 && gt + 3 < 1000) {
      float4 f = *(const float4*)(xp + gt);
      v[0] = f.x; v[1] = f.y; v[2] = f.z; v[3] = f.w;
    } else {
      #pragma unroll
      for (int e = 0; e < 4; e++) { int g2 = gt + e; v[e] = (g2 >= 0 && g2 < 1000) ? xp[g2] : 0.f; }
    }
    #pragma unroll
    for (int e = 0; e < 4; e++) xs[(tt + e) * 88 + kh] = f2bf(v[e]);
  }
  __syncthreads();

  const int lane = tid & 63, wave = tid >> 6;
  const int wt = (wave & 1) * 32;
  const int wo = (wave >> 1) * 16;
  const int m = lane & 15, q = lane >> 4;

  f32x4 acc[2];
  #pragma unroll
  for (int i = 0; i < 2; i++) acc[i] = (f32x4){0.f, 0.f, 0.f, 0.f};

  #pragma unroll 2
  for (int u = 0; u < 65; u++) {
    frag8 A[2][2], B[2];
    #pragma unroll
    for (int tp = 0; tp < 2; tp++)
      #pragma unroll
      for (int kc = 0; kc < 2; kc++)
        A[tp][kc] = *(const frag8*)&xs[(wt + tp * 16 + m + u) * 88 + kc * 32 + q * 8];
    #pragma unroll
    for (int kc = 0; kc < 2; kc++)
      B[kc] = *(const frag8*)(Wb + ((u * 128) + o0 + wo + m) * 64 + kc * 32 + q * 8);
    #pragma unroll
    for (int tp = 0; tp < 2; tp++) {
      acc[tp] = __builtin_amdgcn_mfma_f32_16x16x32_bf16(A[tp][0], B[0], acc[tp], 0, 0, 0);
      acc[tp] = __builtin_amdgcn_mfma_f32_16x16x32_bf16(A[tp][1], B[1], acc[tp], 0, 0, 0);
    }
  }

  {
    int o = o0 + wo + m;
    float s2 = bn2g[o] * BN_S;
    float be = biasEff[o], b2 = bn2b[o];
    #pragma unroll
    for (int tp = 0; tp < 2; tp++) {
      #pragma unroll
      for (int r = 0; r < 4; r++) {
        int t = t0 + wt + tp * 16 + q * 4 + r;
        if (t < 1000)
          z[(b * 128 + o) * 1000 + t] = eluf((acc[tp][r] + be) * s2 + b2);
      }
    }
  }
}

// ============================================================
// k_pool: LDS-staged, coalesced. grid (16 b, 8 og) x 256.
// Same accumulation order as before -> bit-identical.
// ============================================================
__global__ __launch_bounds__(256) void k_pool(const float* __restrict__ z, float* __restrict__ X) {
  __shared__ float zl[16 * 1001];   // 64.06 KB, stride 1001 to spread banks
  int b = blockIdx.x, og = blockIdx.y;
  int tid = threadIdx.x;
  const float* zb = z + (b * 128 + og * 16) * 1000;
  #pragma unroll 1
  for (int r = 0; r < 16; r++)
    for (int c = tid; c < 1000; c += 256) zl[r * 1001 + c] = zb[r * 1000 + c];
  __syncthreads();

  int ol = tid & 15;               // o within group (lane-fast -> coalesced X writes)
  int pb = tid >> 4;               // 0..15
  #pragma unroll 1
  for (int pass = 0; pass < 4; pass++) {
    int p = pb + pass * 16;        // 0..63
    const float* zp = zl + ol * 1001 + p * 15;
    float s = 0.f, ss = 0.f;
    #pragma unroll
    for (int k = 0; k < 50; k++) { float v = zp[k]; s += v; ss = fmaf(v, v, ss); }
    float m = s * 0.02f;
    float var = (ss - s * m) * (1.f / 49.f);
    var = fminf(fmaxf(var, 1e-6f), 1e6f);
    int o = og * 16 + ol;
    X[(b * 64 + p) * 128 + o] = m;
    X[((16 + b) * 64 + p) * 128 + o] = logf(var);
  }
}

// ============================================================
// k_cvt6: encoder weights f32 -> bf16
// ============================================================
__global__ __launch_bounds__(256) void k_cvt6(const float* __restrict__ wq, const float* __restrict__ wk,
                                              const float* __restrict__ wv, const float* __restrict__ wo,
                                              const float* __restrict__ f1w, const float* __restrict__ f2w,
                                              u16* __restrict__ out) {
  int i = blockIdx.x * 256 + threadIdx.x;   // float4 index, total 196608
  if (i >= 196608) return;
  int fi = i * 4;
  const float* src; int off;
  if      (fi < 65536)  { src = wq;  off = fi; }
  else if (fi < 131072) { src = wk;  off = fi - 65536; }
  else if (fi < 196608) { src = wv;  off = fi - 131072; }
  else if (fi < 262144) { src = wo;  off = fi - 196608; }
  else if (fi < 524288) { src = f1w; off = fi - 262144; }
  else                  { src = f2w; off = fi - 524288; }
  float4 v = *(const float4*)(src + off);
  ushort4 p;
  p.x = f2bf(v.x); p.y = f2bf(v.y); p.z = f2bf(v.z); p.w = f2bf(v.w);
  *(ushort4*)(out + fi) = p;
}

// ============================================================
// k_enc: fused 4-layer encoder, 32 blocks x 512 threads (8 waves).
// Round-1 structure + (a) fully-unrolled LN (shfl chains pipeline),
// (b) two-pass attention in registers, (c) B-fragment register prefetch
// one phase early, (d) AOs in Hs (no mid-attention barrier),
// (e) FF double-buffer with 1 barrier/chunk.
// ============================================================
__device__ __forceinline__ void ln128(const float* __restrict__ Xs, u16* __restrict__ Hs,
                                      const float* __restrict__ g, const float* __restrict__ b,
                                      int lane, int wave) {
  float g0 = g[lane], g1 = g[64 + lane], b0 = b[lane], b1 = b[64 + lane];
  #pragma unroll
  for (int rr = 0; rr < 8; rr++) {
    int r = wave * 8 + rr;
    float v0 = Xs[r * 132 + lane], v1 = Xs[r * 132 + 64 + lane];
    float s_ = v0 + v1;
    #pragma unroll
    for (int off = 32; off; off >>= 1) s_ += __shfl_xor(s_, off);
    float mn = s_ * (1.f / 128.f);
    float d0 = v0 - mn, d1 = v1 - mn;
    float qq = d0 * d0 + d1 * d1;
    #pragma unroll
    for (int off = 32; off; off >>= 1) qq += __shfl_xor(qq, off);
    float rs = rsqrtf(qq * (1.f / 128.f) + 1e-5f);
    Hs[r * 136 + lane]      = f2bf(d0 * rs * g0 + b0);
    Hs[r * 136 + 64 + lane] = f2bf(d1 * rs * g1 + b1);
  }
}

// 64-row x 16-col tile GEMM with prefetched B fragments.
__device__ __forceinline__ void gemm_pref(const u16* __restrict__ Asrc, int astride,
                                          const frag8 Bf[4], int m, int q, f32x4 acc[4]) {
  #pragma unroll
  for (int kc = 0; kc < 4; kc++) {
    #pragma unroll
    for (int mt = 0; mt < 4; mt++) {
      frag8 Af = *(const frag8*)(Asrc + (mt * 16 + m) * astride + kc * 32 + q * 8);
      acc[mt] = __builtin_amdgcn_mfma_f32_16x16x32_bf16(Af, Bf[kc], acc[mt], 0, 0, 0);
    }
  }
}

__global__ __launch_bounds__(512, 1) void k_enc(float* __restrict__ X,
                                                const u16* __restrict__ Wenc,
                                                const float* __restrict__ ln1g, const float* __restrict__ ln1b,
                                                const float* __restrict__ ln2g, const float* __restrict__ ln2b,
                                                const float* __restrict__ bq, const float* __restrict__ bk,
                                                const float* __restrict__ bv, const float* __restrict__ bo,
                                                const float* __restrict__ f1b, const float* __restrict__ f2b) {
  __shared__ float Xs[64 * 132];
  __shared__ u16   Hs[64 * 136];      // LN out; AOs aliases
  __shared__ float QKV[3 * 64 * 132]; // F1a/F1b alias after attention
  float* Qs = QKV;
  float* Ks = QKV + 64 * 132;
  float* Vs = QKV + 2 * 64 * 132;
  u16* AOs  = Hs;
  u16* F1a  = (u16*)QKV;
  u16* F1b_ = (u16*)QKV + 64 * 136;

  const int tid = threadIdx.x;
  const int lane = tid & 63, wave = tid >> 6;
  const int m = lane & 15, q = lane >> 4;
  const int n0 = wave * 16;
  float* Xg = X + blockIdx.x * 64 * 128;

  const u16* WQ  = Wenc;
  const u16* WK  = Wenc + 65536;
  const u16* WV  = Wenc + 131072;
  const u16* WO  = Wenc + 196608;
  const u16* F1W = Wenc + 262144;
  const u16* F2W = Wenc + 524288;

  for (int i = tid; i < 8192; i += 512) Xs[(i >> 7) * 132 + (i & 127)] = Xg[i];
  __syncthreads();

  #pragma unroll 1
  for (int l = 0; l < 4; l++) {
    const u16* wqb  = WQ  + l * 16384;
    const u16* wkb  = WK  + l * 16384;
    const u16* wvb  = WV  + l * 16384;
    const u16* wob  = WO  + l * 16384;
    const u16* f1wb = F1W + l * 65536;
    const u16* f2wb = F2W + l * 65536;

    // ---- prefetch QKV B-frags (latency hides under LN1) ----
    frag8 fq[4], fk[4], fv[4];
    #pragma unroll
    for (int kc = 0; kc < 4; kc++) {
      fq[kc] = *(const frag8*)(wqb + (n0 + m) * 128 + kc * 32 + q * 8);
      fk[kc] = *(const frag8*)(wkb + (n0 + m) * 128 + kc * 32 + q * 8);
      fv[kc] = *(const frag8*)(wvb + (n0 + m) * 128 + kc * 32 + q * 8);
    }

    // ---- LN1 -> Hs ----
    ln128(Xs, Hs, ln1g + l * 128, ln1b + l * 128, lane, wave);
    __syncthreads();

    // ---- QKV (prefetch O-proj frags at phase start) ----
    frag8 fo[4];
    #pragma unroll
    for (int kc = 0; kc < 4; kc++)
      fo[kc] = *(const frag8*)(wob + (n0 + m) * 128 + kc * 32 + q * 8);
    {
      f32x4 aq[4], ak[4], av[4];
      #pragma unroll
      for (int mt = 0; mt < 4; mt++) { aq[mt] = (f32x4){0,0,0,0}; ak[mt] = (f32x4){0,0,0,0}; av[mt] = (f32x4){0,0,0,0}; }
      gemm_pref(Hs, 136, fq, m, q, aq);
      gemm_pref(Hs, 136, fk, m, q, ak);
      gemm_pref(Hs, 136, fv, m, q, av);
      float bqv = bq[l * 128 + n0 + m];
      float bkv = bk[l * 128 + n0 + m];
      float bvv = bv[l * 128 + n0 + m];
      #pragma unroll
      for (int mt = 0; mt < 4; mt++)
        #pragma unroll
        for (int r = 0; r < 4; r++) {
          int row = mt * 16 + q * 4 + r;
          Qs[row * 132 + n0 + m] = aq[mt][r] + bqv;
          Ks[row * 132 + n0 + m] = ak[mt][r] + bkv;
          Vs[row * 132 + n0 + m] = av[mt][r] + bvv;
        }
    }
    __syncthreads();

    // ---- attention (two-pass, registers). wave=head, lane=query row.
    //      Prefetch FF1 chunk-0 frags at phase start. ----
    frag8 f1f[4];
    #pragma unroll
    for (int kc = 0; kc < 4; kc++)
      f1f[kc] = *(const frag8*)(f1wb + (n0 + m) * 128 + kc * 32 + q * 8);
    {
      const int h = wave, qr = lane;
      float qv[16];
      {
        const float4* qp = (const float4*)(Qs + qr * 132 + h * 16);
        #pragma unroll
        for (int j = 0; j < 4; j++) {
          float4 t = qp[j];
          qv[j * 4 + 0] = t.x; qv[j * 4 + 1] = t.y; qv[j * 4 + 2] = t.z; qv[j * 4 + 3] = t.w;
        }
      }
      const float* kbase = Ks + h * 16;
      const float* vbase = Vs + h * 16;
      float s_[64];
      float m0 = -1e30f, m1 = -1e30f, m2 = -1e30f, m3 = -1e30f;
      #pragma unroll
      for (int k4 = 0; k4 < 64; k4 += 4) {
        #pragma unroll
        for (int e = 0; e < 4; e++) {
          const float4* kp = (const float4*)(kbase + (k4 + e) * 132);
          float4 k0 = kp[0], k1 = kp[1], k2 = kp[2], k3 = kp[3];
          float d0 = qv[0] * k0.x + qv[1] * k0.y + qv[2] * k0.z + qv[3] * k0.w;
          float d1 = qv[4] * k1.x + qv[5] * k1.y + qv[6] * k1.z + qv[7] * k1.w;
          float d2 = qv[8] * k2.x + qv[9] * k2.y + qv[10] * k2.z + qv[11] * k2.w;
          float d3 = qv[12] * k3.x + qv[13] * k3.y + qv[14] * k3.z + qv[15] * k3.w;
          float sc = ((d0 + d1) + (d2 + d3)) * 0.25f;
          s_[k4 + e] = sc;
          if (e == 0) m0 = fmaxf(m0, sc);
          else if (e == 1) m1 = fmaxf(m1, sc);
          else if (e == 2) m2 = fmaxf(m2, sc);
          else m3 = fmaxf(m3, sc);
        }
      }
      float mx = fmaxf(fmaxf(m0, m1), fmaxf(m2, m3));
      float l_ = 0.f;
      float o[16];
      #pragma unroll
      for (int j = 0; j < 16; j++) o[j] = 0.f;
      #pragma unroll
      for (int k = 0; k < 64; k++) {
        float p = __expf(s_[k] - mx);
        l_ += p;
        const float4* vp = (const float4*)(vbase + k * 132);
        float4 v0 = vp[0], v1 = vp[1], v2 = vp[2], v3 = vp[3];
        o[0]  = fmaf(p, v0.x, o[0]);  o[1]  = fmaf(p, v0.y, o[1]);
        o[2]  = fmaf(p, v0.z, o[2]);  o[3]  = fmaf(p, v0.w, o[3]);
        o[4]  = fmaf(p, v1.x, o[4]);  o[5]  = fmaf(p, v1.y, o[5]);
        o[6]  = fmaf(p, v1.z, o[6]);  o[7]  = fmaf(p, v1.w, o[7]);
        o[8]  = fmaf(p, v2.x, o[8]);  o[9]  = fmaf(p, v2.y, o[9]);
        o[10] = fmaf(p, v2.z, o[10]); o[11] = fmaf(p, v2.w, o[11]);
        o[12] = fmaf(p, v3.x, o[12]); o[13] = fmaf(p, v3.y, o[13]);
        o[14] = fmaf(p, v3.z, o[14]); o[15] = fmaf(p, v3.w, o[15]);
      }
      float inv = 1.f / l_;
      u16* aop = AOs + qr * 136 + h * 16;
      #pragma unroll
      for (int j = 0; j < 16; j++) aop[j] = f2bf(o[j] * inv);
    }
    __syncthreads();

    // ---- O-proj + residual into Xs ----
    {
      f32x4 ao4[4];
      #pragma unroll
      for (int mt = 0; mt < 4; mt++) ao4[mt] = (f32x4){0,0,0,0};
      gemm_pref(AOs, 136, fo, m, q, ao4);
      float bov = bo[l * 128 + n0 + m];
      #pragma unroll
      for (int mt = 0; mt < 4; mt++)
        #pragma unroll
        for (int r = 0; r < 4; r++)
          Xs[(mt * 16 + q * 4 + r) * 132 + n0 + m] += ao4[mt][r] + bov;
    }
    __syncthreads();

    // ---- LN2 -> Hs ----
    ln128(Xs, Hs, ln2g + l * 128, ln2b + l * 128, lane, wave);
    __syncthreads();

    // ---- FF: 4 chunks of 128 F1-cols; double-buffered; frags pipelined ----
    {
      f32x4 acc2[4];
      #pragma unroll
      for (int mt = 0; mt < 4; mt++) acc2[mt] = (f32x4){0,0,0,0};
      #pragma unroll 1
      for (int c = 0; c < 4; c++) {
        frag8 f2f[4];
        #pragma unroll
        for (int kc = 0; kc < 4; kc++)
          f2f[kc] = *(const frag8*)(f2wb + (n0 + m) * 512 + c * 128 + kc * 32 + q * 8);
        u16* F1c = (c & 1) ? F1b_ : F1a;
        {
          f32x4 a1[4];
          #pragma unroll
          for (int mt = 0; mt < 4; mt++) a1[mt] = (f32x4){0,0,0,0};
          gemm_pref(Hs, 136, f1f, m, q, a1);
          float b1v = f1b[l * 512 + c * 128 + n0 + m];
          #pragma unroll
          for (int mt = 0; mt < 4; mt++)
            #pragma unroll
            for (int r = 0; r < 4; r++)
              F1c[(mt * 16 + q * 4 + r) * 136 + n0 + m] = f2bf(geluf(a1[mt][r] + b1v));
        }
        __syncthreads();
        if (c < 3) {
          #pragma unroll
          for (int kc = 0; kc < 4; kc++)
            f1f[kc] = *(const frag8*)(f1wb + ((c + 1) * 128 + n0 + m) * 128 + kc * 32 + q * 8);
        }
        gemm_pref(F1c, 136, f2f, m, q, acc2);
        // no barrier: next chunk writes the other buffer
      }
      float b2v = f2b[l * 128 + n0 + m];
      #pragma unroll
      for (int mt = 0; mt < 4; mt++)
        #pragma unroll
        for (int r = 0; r < 4; r++)
          Xs[(mt * 16 + q * 4 + r) * 132 + n0 + m] += acc2[mt][r] + b2v;
    }
    __syncthreads();
  }

  for (int i = tid; i < 8192; i += 512) Xg[i] = Xs[(i >> 7) * 132 + (i & 127)];
}

// ============================================================
// k_head1
// ============================================================
__global__ __launch_bounds__(256) void k_head1(const float* __restrict__ X, const float* __restrict__ ew,
                                               const float* __restrict__ eb, const float* __restrict__ g3,
                                               const float* __restrict__ b3, float* __restrict__ G) {
  __shared__ float Xs[2][8192];   // 64 KB
  int b = blockIdx.x, ot = blockIdx.y;
  int tid = threadIdx.x;
  {
    const float4* x1 = (const float4*)(X + b * 8192);
    const float4* x2 = (const float4*)(X + (16 + b) * 8192);
    float4* s1 = (float4*)&Xs[0][0];
    float4* s2 = (float4*)&Xs[1][0];
    for (int i = tid; i < 2048; i += 256) { s1[i] = x1[i]; s2[i] = x2[i]; }
  }
  __syncthreads();
  int w = tid & 127, og = tid >> 7;
  int oc0 = ot * 16 + og * 8;
  float a[8] = {};
  for (int ic = 0; ic < 64; ic++) {
    float x1v = Xs[0][ic * 128 + w], x2v = Xs[1][ic * 128 + w];
    #pragma unroll
    for (int j = 0; j < 8; j++) {
      a[j] = fmaf(ew[((oc0 + j) * 64 + ic) * 2 + 0], x1v, a[j]);
      a[j] = fmaf(ew[((oc0 + j) * 64 + ic) * 2 + 1], x2v, a[j]);
    }
  }
  #pragma unroll
  for (int j = 0; j < 8; j++) {
    int oc = oc0 + j;
    float v = (a[j] + eb[oc]) * (g3[oc] * BN_S) + b3[oc];
    G[(b * 64 + oc) * 128 + w] = eluf(v);
  }
}

// ============================================================
// k_head2
// ============================================================
__global__ __launch_bounds__(256) void k_head2(const float* __restrict__ G, const float* __restrict__ cw,
                                               const float* __restrict__ cb, float* __restrict__ out) {
  __shared__ float red[256];
  int b = blockIdx.x, c = blockIdx.y, tid = threadIdx.x;
  const float4* g4 = (const float4*)(G + b * 8192);
  const float4* c4 = (const float4*)(cw + c * 8192);
  float p = 0.f;
  for (int i = tid; i < 2048; i += 256) {
    float4 g = g4[i], w = c4[i];
    p += g.x * w.x + g.y * w.y + g.z * w.z + g.w * w.w;
  }
  red[tid] = p;
  __syncthreads();
  for (int s = 128; s > 0; s >>= 1) {
    if (tid < s) red[tid] += red[tid + s];
    __syncthreads();
  }
  if (tid == 0) out[b * 4 + c] = red[0] + cb[c];
}

// ============================================================
extern "C" void kernel_launch(void* const* d_in, const int* in_sizes, int n_in,
                              void* d_out, int out_size, void* d_ws, size_t ws_size,
                              hipStream_t stream) {
  const float* x    = (const float*)d_in[0];
  const float* tw1  = (const float*)d_in[1];  const float* tb1 = (const float*)d_in[2];
  const float* tw2  = (const float*)d_in[3];  const float* tb2 = (const float*)d_in[4];
  const float* tw3  = (const float*)d_in[5];  const float* tb3 = (const float*)d_in[6];
  const float* tw4  = (const float*)d_in[7];  const float* tb4 = (const float*)d_in[8];
  const float* bn1g = (const float*)d_in[9];  const float* bn1b = (const float*)d_in[10];
  const float* sw   = (const float*)d_in[11]; const float* sb   = (const float*)d_in[12];
  const float* bn2g = (const float*)d_in[13]; const float* bn2b = (const float*)d_in[14];
  const float* ln1g = (const float*)d_in[15]; const float* ln1b = (const float*)d_in[16];
  const float* ln2g = (const float*)d_in[17]; const float* ln2b = (const float*)d_in[18];
  const float* wq   = (const float*)d_in[19]; const float* bq   = (const float*)d_in[20];
  const float* wk   = (const float*)d_in[21]; const float* bk   = (const float*)d_in[22];
  const float* wv   = (const float*)d_in[23]; const float* bv   = (const float*)d_in[24];
  const float* wo   = (const float*)d_in[25]; const float* bo   = (const float*)d_in[26];
  const float* f1w  = (const float*)d_in[27]; const float* f1b  = (const float*)d_in[28];
  const float* f2w  = (const float*)d_in[29]; const float* f2b  = (const float*)d_in[30];
  const float* ew   = (const float*)d_in[31]; const float* eb   = (const float*)d_in[32];
  const float* g3   = (const float*)d_in[33]; const float* b3   = (const float*)d_in[34];
  const float* cw   = (const float*)d_in[35]; const float* cb   = (const float*)d_in[36];

  float* ws      = (float*)d_ws;
  float* tws1    = ws;               // 8320
  float* c1      = ws + 8320;        // 128
  float* biasEff = ws + 8448;        // 128
  u16*   Wb      = (u16*)(ws + 8576);// 532480 bf16 [u][o][kh] (1.04 MB)
  float* z       = ws + 541056;      // 2048000 [b][o][t]; reused as G after pool
  float* X       = ws + 2589056;     // 262144  [2048][128]
  u16*   Wenc    = (u16*)(ws + 3113344); // 786432 bf16 encoder weights (1.5 MB)
  float* G       = z;                // 131072 (z dead after k_pool)

  k_cvt6<<<768, 256, 0, stream>>>(wq, wk, wv, wo, f1w, f2w, Wenc);
  k_tws1<<<33, 256, 0, stream>>>(tw1, tw2, tw3, tw4, tb1, tb2, tb3, tb4, bn1g, bn1b, tws1, c1);
  k_weff<<<128, 256, 0, stream>>>(sw, sb, tws1, c1, Wb, biasEff);
  k_conv<<<dim3(16, 4, 16), 256, 0, stream>>>(x, Wb, biasEff, bn2g, bn2b, z);
  k_pool<<<dim3(16, 8), 256, 0, stream>>>(z, X);

  k_enc<<<32, 512, 0, stream>>>(X, Wenc, ln1g, ln1b, ln2g, ln2b, bq, bk, bv, bo, f1b, f2b);

  k_head1<<<dim3(16, 4), 256, 0, stream>>>(X, ew, eb, g3, b3, G);
  k_head2<<<dim3(16, 4), 256, 0, stream>>>(G, cw, cb, (float*)d_out);
}

// Round 5
// 384.210 us; speedup vs baseline: 1.1820x; 1.0535x over previous
//
#include <hip/hip_runtime.h>
#include <math.h>

typedef unsigned short u16;
typedef __attribute__((ext_vector_type(8))) short frag8;   // 8 bf16 = 4 VGPR
typedef __attribute__((ext_vector_type(4))) float f32x4;   // MFMA acc

__device__ __forceinline__ float eluf(float v) { return v > 0.f ? v : expm1f(v); }
__device__ __forceinline__ float geluf(float v) {
  return 0.5f * v * (1.f + erff(v * 0.70710678118654752f));
}
__device__ __forceinline__ u16 f2bf(float f) {
  union { float f; unsigned int i; } v; v.f = f;
  return (u16)((v.i + 0x7fffu + ((v.i >> 16) & 1u)) >> 16);
}

#define BN_S 0.99999500003749969f   /* 1/sqrt(1+1e-5) */

// ============================================================
// k_tws1
// ============================================================
__global__ void k_tws1(const float* tw1, const float* tw2, const float* tw3, const float* tw4,
                       const float* tb1, const float* tb2, const float* tb3, const float* tb4,
                       const float* bn1g, const float* bn1b,
                       float* tws1, float* c1) {
  int idx = blockIdx.x * 256 + threadIdx.x;
  if (idx < 8320) {
    int i = idx / 65, u = idx - i * 65;
    int g = i >> 5, il = i & 31;
    const float* tws[4] = {tw1, tw2, tw3, tw4};
    const int P[4] = {7, 12, 25, 32};
    int c = u - 32;
    float s1 = bn1g[i] * BN_S;
    float val = 0.f;
    int p = P[g];
    if (c >= -p && c <= p) val = s1 * tws[g][il * (2 * p + 1) + (c + p)];
    tws1[idx] = val;
  } else if (idx < 8448) {
    int i = idx - 8320;
    int g = i >> 5, il = i & 31;
    const float* tbs[4] = {tb1, tb2, tb3, tb4};
    float s1 = bn1g[i] * BN_S;
    c1[i] = s1 * tbs[g][il] + bn1b[i];
  }
}

// ============================================================
// k_weff: one block per o. Bit-identical accumulation.
// ============================================================
__global__ __launch_bounds__(256) void k_weff(const float* __restrict__ sw, const float* __restrict__ sb,
                                              const float* __restrict__ tws1, const float* __restrict__ c1,
                                              u16* __restrict__ Wb, float* __restrict__ biasEff) {
  __shared__ float swl[8192];   // [i][kh]
  __shared__ float tl[8320];    // [i][u]
  const int tid = threadIdx.x, lane = tid & 63, wave = tid >> 6;
  const int o = blockIdx.x;
  for (int idx = tid; idx < 8192; idx += 256) swl[idx] = sw[o * 8192 + idx];
  for (int idx = tid; idx < 8320; idx += 256) tl[idx] = tws1[idx];
  __syncthreads();

  #pragma unroll 1
  for (int j = 0; j < 4; j++) {
    int u0 = (wave + 4 * j) * 4;
    float a[4][4];
    #pragma unroll
    for (int uu = 0; uu < 4; uu++)
      #pragma unroll
      for (int r = 0; r < 4; r++) a[uu][r] = 0.f;
    #pragma unroll 1
    for (int i = 0; i < 128; i += 4) {
      #pragma unroll
      for (int ii = 0; ii < 4; ii++) {
        float s = swl[(i + ii) * 64 + lane];
        #pragma unroll
        for (int uu = 0; uu < 4; uu++)
          a[uu][ii] = fmaf(s, tl[(i + ii) * 65 + u0 + uu], a[uu][ii]);
      }
    }
    #pragma unroll
    for (int uu = 0; uu < 4; uu++)
      Wb[((u0 + uu) * 128 + o) * 64 + lane] = f2bf((a[uu][0] + a[uu][1]) + (a[uu][2] + a[uu][3]));
  }

  if (wave == 0) {   // u = 64
    float a[4] = {0.f, 0.f, 0.f, 0.f};
    #pragma unroll 1
    for (int i = 0; i < 128; i += 4) {
      #pragma unroll
      for (int ii = 0; ii < 4; ii++)
        a[ii] = fmaf(swl[(i + ii) * 64 + lane], tl[(i + ii) * 65 + 64], a[ii]);
    }
    Wb[(64 * 128 + o) * 64 + lane] = f2bf((a[0] + a[1]) + (a[2] + a[3]));
  } else if (wave == 1) {
    float pa = 0.f;
    #pragma unroll 8
    for (int i = 0; i < 128; i++)
      pa = fmaf(swl[i * 64 + lane], c1[i], pa);
    #pragma unroll
    for (int off = 32; off; off >>= 1) pa += __shfl_xor(pa, off);
    if (lane == 0) biasEff[o] = pa + sb[o];
  }
}

// ============================================================
// k_conv (MFMA): o-tile 32, grid (16,4,16).
// ============================================================
__global__ __launch_bounds__(256) void k_conv(const float* __restrict__ x,
                                              const u16* __restrict__ Wb,
                                              const float* __restrict__ biasEff,
                                              const float* __restrict__ bn2g, const float* __restrict__ bn2b,
                                              float* __restrict__ z) {
  __shared__ u16 xs[128 * 88];
  const int tid = threadIdx.x;
  const int t0 = blockIdx.x * 64;
  const int o0 = blockIdx.y * 32;
  const int b  = blockIdx.z;

  #pragma unroll
  for (int i = 0; i < 8; i++) {
    int pos = tid + i * 256;
    int kh = pos >> 5;
    int tt = (pos & 31) * 4;
    int gt = t0 - 32 + tt;
    const float* xp = x + (b * 64 + kh) * 1000;
    float v[4];
    if (gt >= 0 && gt + 3 < 1000) {
      float4 f = *(const float4*)(xp + gt);
      v[0] = f.x; v[1] = f.y; v[2] = f.z; v[3] = f.w;
    } else {
      #pragma unroll
      for (int e = 0; e < 4; e++) { int g2 = gt + e; v[e] = (g2 >= 0 && g2 < 1000) ? xp[g2] : 0.f; }
    }
    #pragma unroll
    for (int e = 0; e < 4; e++) xs[(tt + e) * 88 + kh] = f2bf(v[e]);
  }
  __syncthreads();

  const int lane = tid & 63, wave = tid >> 6;
  const int wt = (wave & 1) * 32;
  const int wo = (wave >> 1) * 16;
  const int m = lane & 15, q = lane >> 4;

  f32x4 acc[2];
  #pragma unroll
  for (int i = 0; i < 2; i++) acc[i] = (f32x4){0.f, 0.f, 0.f, 0.f};

  #pragma unroll 2
  for (int u = 0; u < 65; u++) {
    frag8 A[2][2], B[2];
    #pragma unroll
    for (int tp = 0; tp < 2; tp++)
      #pragma unroll
      for (int kc = 0; kc < 2; kc++)
        A[tp][kc] = *(const frag8*)&xs[(wt + tp * 16 + m + u) * 88 + kc * 32 + q * 8];
    #pragma unroll
    for (int kc = 0; kc < 2; kc++)
      B[kc] = *(const frag8*)(Wb + ((u * 128) + o0 + wo + m) * 64 + kc * 32 + q * 8);
    #pragma unroll
    for (int tp = 0; tp < 2; tp++) {
      acc[tp] = __builtin_amdgcn_mfma_f32_16x16x32_bf16(A[tp][0], B[0], acc[tp], 0, 0, 0);
      acc[tp] = __builtin_amdgcn_mfma_f32_16x16x32_bf16(A[tp][1], B[1], acc[tp], 0, 0, 0);
    }
  }

  {
    int o = o0 + wo + m;
    float s2 = bn2g[o] * BN_S;
    float be = biasEff[o], b2 = bn2b[o];
    #pragma unroll
    for (int tp = 0; tp < 2; tp++) {
      #pragma unroll
      for (int r = 0; r < 4; r++) {
        int t = t0 + wt + tp * 16 + q * 4 + r;
        if (t < 1000)
          z[(b * 128 + o) * 1000 + t] = eluf((acc[tp][r] + be) * s2 + b2);
      }
    }
  }
}

// ============================================================
// k_pool: LDS-staged, coalesced. Bit-identical accumulation.
// ============================================================
__global__ __launch_bounds__(256) void k_pool(const float* __restrict__ z, float* __restrict__ X) {
  __shared__ float zl[16 * 1001];
  int b = blockIdx.x, og = blockIdx.y;
  int tid = threadIdx.x;
  const float* zb = z + (b * 128 + og * 16) * 1000;
  #pragma unroll 1
  for (int r = 0; r < 16; r++)
    for (int c = tid; c < 1000; c += 256) zl[r * 1001 + c] = zb[r * 1000 + c];
  __syncthreads();

  int ol = tid & 15;
  int pb = tid >> 4;
  #pragma unroll 1
  for (int pass = 0; pass < 4; pass++) {
    int p = pb + pass * 16;
    const float* zp = zl + ol * 1001 + p * 15;
    float s = 0.f, ss = 0.f;
    #pragma unroll
    for (int k = 0; k < 50; k++) { float v = zp[k]; s += v; ss = fmaf(v, v, ss); }
    float m = s * 0.02f;
    float var = (ss - s * m) * (1.f / 49.f);
    var = fminf(fmaxf(var, 1e-6f), 1e6f);
    int o = og * 16 + ol;
    X[(b * 64 + p) * 128 + o] = m;
    X[((16 + b) * 64 + p) * 128 + o] = logf(var);
  }
}

// ============================================================
// k_cvt6: encoder weights f32 -> bf16
// ============================================================
__global__ __launch_bounds__(256) void k_cvt6(const float* __restrict__ wq, const float* __restrict__ wk,
                                              const float* __restrict__ wv, const float* __restrict__ wo,
                                              const float* __restrict__ f1w, const float* __restrict__ f2w,
                                              u16* __restrict__ out) {
  int i = blockIdx.x * 256 + threadIdx.x;
  if (i >= 196608) return;
  int fi = i * 4;
  const float* src; int off;
  if      (fi < 65536)  { src = wq;  off = fi; }
  else if (fi < 131072) { src = wk;  off = fi - 65536; }
  else if (fi < 196608) { src = wv;  off = fi - 131072; }
  else if (fi < 262144) { src = wo;  off = fi - 196608; }
  else if (fi < 524288) { src = f1w; off = fi - 262144; }
  else                  { src = f2w; off = fi - 524288; }
  float4 v = *(const float4*)(src + off);
  ushort4 p;
  p.x = f2bf(v.x); p.y = f2bf(v.y); p.z = f2bf(v.z); p.w = f2bf(v.w);
  *(ushort4*)(out + fi) = p;
}

// ============================================================
// k_enc: fused 4-layer encoder, 32 blocks x 512 threads (8 waves).
// MFMA attention (bf16 Q/K/V/P), A-fragment hoisting,
// QKV->attention fused with no barrier (wave-local head buffers).
// LDS (151 KB):
//   Xs f32[64][132] | Hs bf16[64][136] | Qb bf16[8][64][32] (zero-padded K)
//   Kb bf16[8][64][32] | VtAO = Vt bf16[8][16][80] ++ AOs bf16[64][136]
//   (F1a/F1b double-buffer aliases VtAO)
// ============================================================
__device__ __forceinline__ void ln128(const float* __restrict__ Xs, u16* __restrict__ Hs,
                                      const float* __restrict__ g, const float* __restrict__ b,
                                      int lane, int wave) {
  float g0 = g[lane], g1 = g[64 + lane], b0 = b[lane], b1 = b[64 + lane];
  #pragma unroll
  for (int rr = 0; rr < 8; rr++) {
    int r = wave * 8 + rr;
    float v0 = Xs[r * 132 + lane], v1 = Xs[r * 132 + 64 + lane];
    float s_ = v0 + v1;
    #pragma unroll
    for (int off = 32; off; off >>= 1) s_ += __shfl_xor(s_, off);
    float mn = s_ * (1.f / 128.f);
    float d0 = v0 - mn, d1 = v1 - mn;
    float qq = d0 * d0 + d1 * d1;
    #pragma unroll
    for (int off = 32; off; off >>= 1) qq += __shfl_xor(qq, off);
    float rs = rsqrtf(qq * (1.f / 128.f) + 1e-5f);
    Hs[r * 136 + lane]      = f2bf(d0 * rs * g0 + b0);
    Hs[r * 136 + 64 + lane] = f2bf(d1 * rs * g1 + b1);
  }
}

// GEMM with hoisted A-frags (Ar) and prefetched B-frags.
__device__ __forceinline__ void gemm_hoist(const frag8 Ar[4][4], const frag8 Bf[4], f32x4 acc[4]) {
  #pragma unroll
  for (int kc = 0; kc < 4; kc++)
    #pragma unroll
    for (int mt = 0; mt < 4; mt++)
      acc[mt] = __builtin_amdgcn_mfma_f32_16x16x32_bf16(Ar[mt][kc], Bf[kc], acc[mt], 0, 0, 0);
}

__device__ __forceinline__ void gemm_pref(const u16* __restrict__ Asrc, int astride,
                                          const frag8 Bf[4], int m, int q, f32x4 acc[4]) {
  #pragma unroll
  for (int kc = 0; kc < 4; kc++) {
    #pragma unroll
    for (int mt = 0; mt < 4; mt++) {
      frag8 Af = *(const frag8*)(Asrc + (mt * 16 + m) * astride + kc * 32 + q * 8);
      acc[mt] = __builtin_amdgcn_mfma_f32_16x16x32_bf16(Af, Bf[kc], acc[mt], 0, 0, 0);
    }
  }
}

__global__ __launch_bounds__(512, 1) void k_enc(float* __restrict__ X,
                                                const u16* __restrict__ Wenc,
                                                const float* __restrict__ ln1g, const float* __restrict__ ln1b,
                                                const float* __restrict__ ln2g, const float* __restrict__ ln2b,
                                                const float* __restrict__ bq, const float* __restrict__ bk,
                                                const float* __restrict__ bv, const float* __restrict__ bo,
                                                const float* __restrict__ f1b, const float* __restrict__ f2b) {
  __shared__ __align__(16) float Xs[64 * 132];
  __shared__ __align__(16) u16   Hs[64 * 136];
  __shared__ __align__(16) u16   Qb[8 * 64 * 32];
  __shared__ __align__(16) u16   Kb[8 * 64 * 32];
  __shared__ __align__(16) u16   VtAO[8 * 16 * 80 + 64 * 136];
  u16* Vt   = VtAO;                 // [8][16][80]
  u16* AOs  = VtAO + 10240;         // [64][136]
  u16* F1a  = VtAO;                 // [64][136] (FF phase; Vt dead)
  u16* F1b_ = VtAO + 8704;          // [64][136]

  const int tid = threadIdx.x;
  const int lane = tid & 63, wave = tid >> 6;
  const int m = lane & 15, q = lane >> 4;
  const int n0 = wave * 16;
  float* Xg = X + blockIdx.x * 64 * 128;

  const u16* WQ  = Wenc;
  const u16* WK  = Wenc + 65536;
  const u16* WV  = Wenc + 131072;
  const u16* WO  = Wenc + 196608;
  const u16* F1W = Wenc + 262144;
  const u16* F2W = Wenc + 524288;

  u16* Qh = Qb + wave * 2048;       // this wave's head buffers
  u16* Kh = Kb + wave * 2048;
  u16* Vh = Vt + wave * 1280;

  for (int i = tid; i < 8192; i += 512) Xs[(i >> 7) * 132 + (i & 127)] = Xg[i];
  __syncthreads();

  #pragma unroll 1
  for (int l = 0; l < 4; l++) {
    const u16* wqb  = WQ  + l * 16384;
    const u16* wkb  = WK  + l * 16384;
    const u16* wvb  = WV  + l * 16384;
    const u16* wob  = WO  + l * 16384;
    const u16* f1wb = F1W + l * 65536;
    const u16* f2wb = F2W + l * 65536;

    // ---- prefetch QKV B-frags (hide under LN1) ----
    frag8 fq[4], fk[4], fv[4];
    #pragma unroll
    for (int kc = 0; kc < 4; kc++) {
      fq[kc] = *(const frag8*)(wqb + (n0 + m) * 128 + kc * 32 + q * 8);
      fk[kc] = *(const frag8*)(wkb + (n0 + m) * 128 + kc * 32 + q * 8);
      fv[kc] = *(const frag8*)(wvb + (n0 + m) * 128 + kc * 32 + q * 8);
    }

    // ---- LN1 -> Hs ----
    ln128(Xs, Hs, ln1g + l * 128, ln1b + l * 128, lane, wave);
    __syncthreads();

    // ---- QKV gemms (A hoisted) + bf16 stores into head buffers ----
    frag8 fo[4];
    #pragma unroll
    for (int kc = 0; kc < 4; kc++)
      fo[kc] = *(const frag8*)(wob + (n0 + m) * 128 + kc * 32 + q * 8);
    {
      frag8 Ar[4][4];
      #pragma unroll
      for (int mt = 0; mt < 4; mt++)
        #pragma unroll
        for (int kc = 0; kc < 4; kc++)
          Ar[mt][kc] = *(const frag8*)&Hs[(mt * 16 + m) * 136 + kc * 32 + q * 8];
      f32x4 aq[4], ak[4], av[4];
      #pragma unroll
      for (int mt = 0; mt < 4; mt++) { aq[mt] = (f32x4){0,0,0,0}; ak[mt] = (f32x4){0,0,0,0}; av[mt] = (f32x4){0,0,0,0}; }
      gemm_hoist(Ar, fq, aq);
      gemm_hoist(Ar, fk, ak);
      gemm_hoist(Ar, fv, av);
      float bqv = bq[l * 128 + n0 + m];
      float bkv = bk[l * 128 + n0 + m];
      float bvv = bv[l * 128 + n0 + m];
      #pragma unroll
      for (int mt = 0; mt < 4; mt++)
        #pragma unroll
        for (int r = 0; r < 4; r++) {
          int row = mt * 16 + q * 4 + r;
          Qh[row * 32 + m] = f2bf((aq[mt][r] + bqv) * 0.25f);  // fold 1/sqrt(dk), exact
          Kh[row * 32 + m] = f2bf(ak[mt][r] + bkv);
          Vh[m * 80 + row] = f2bf(av[mt][r] + bvv);            // V transposed [d][key]
        }
      // zero the K-pad (cols 16..31) of Q/K for the K=32 MFMA
      frag8 z8 = {};
      *(frag8*)&Qh[lane * 32 + 16] = z8;
      *(frag8*)&Qh[lane * 32 + 24] = z8;
      *(frag8*)&Kh[lane * 32 + 16] = z8;
      *(frag8*)&Kh[lane * 32 + 24] = z8;
    }

    // ---- attention (wave-local head; NO barrier since QKV) ----
    frag8 f1f[4];
    #pragma unroll
    for (int kc = 0; kc < 4; kc++)
      f1f[kc] = *(const frag8*)(f1wb + (n0 + m) * 128 + kc * 32 + q * 8);
    {
      // scores: S = (0.25*Q) . K^T via 16 MFMAs (K=32, upper half zero)
      f32x4 sacc[4][4];
      frag8 QA[4], KB[4];
      #pragma unroll
      for (int mt = 0; mt < 4; mt++) QA[mt] = *(const frag8*)&Qh[(mt * 16 + m) * 32 + q * 8];
      #pragma unroll
      for (int np = 0; np < 4; np++) KB[np] = *(const frag8*)&Kh[(np * 16 + m) * 32 + q * 8];
      #pragma unroll
      for (int mt = 0; mt < 4; mt++)
        #pragma unroll
        for (int np = 0; np < 4; np++)
          sacc[mt][np] = __builtin_amdgcn_mfma_f32_16x16x32_bf16(QA[mt], KB[np], (f32x4){0,0,0,0}, 0, 0, 0);

      // softmax over keys: row = mt*16+q*4+r; keys spread over np regs x m lanes
      float inv[4][4];
      #pragma unroll
      for (int mt = 0; mt < 4; mt++)
        #pragma unroll
        for (int r = 0; r < 4; r++) {
          float mx = fmaxf(fmaxf(sacc[mt][0][r], sacc[mt][1][r]), fmaxf(sacc[mt][2][r], sacc[mt][3][r]));
          #pragma unroll
          for (int off = 1; off < 16; off <<= 1) mx = fmaxf(mx, __shfl_xor(mx, off));
          #pragma unroll
          for (int np = 0; np < 4; np++) sacc[mt][np][r] = __expf(sacc[mt][np][r] - mx);
          float s_ = ((sacc[mt][0][r] + sacc[mt][1][r]) + (sacc[mt][2][r] + sacc[mt][3][r]));
          #pragma unroll
          for (int off = 1; off < 16; off <<= 1) s_ += __shfl_xor(s_, off);
          inv[mt][r] = 1.f / s_;
        }

      // write normalized P (bf16) into Qh (keys 0..31) / Kh (keys 32..63)
      #pragma unroll
      for (int mt = 0; mt < 4; mt++)
        #pragma unroll
        for (int np = 0; np < 4; np++) {
          u16* dst = (np < 2) ? Qh : Kh;
          int col = (np & 1) * 16 + m;
          #pragma unroll
          for (int r = 0; r < 4; r++)
            dst[(mt * 16 + q * 4 + r) * 32 + col] = f2bf(sacc[mt][np][r] * inv[mt][r]);
        }

      // PV: O = P . V  (2 K-chunks of 32 keys)
      f32x4 oacc[4];
      #pragma unroll
      for (int mt = 0; mt < 4; mt++) oacc[mt] = (f32x4){0,0,0,0};
      #pragma unroll
      for (int kc = 0; kc < 2; kc++) {
        frag8 VB = *(const frag8*)&Vh[m * 80 + kc * 32 + q * 8];
        const u16* Psrc = kc ? Kh : Qh;
        #pragma unroll
        for (int mt = 0; mt < 4; mt++) {
          frag8 PA = *(const frag8*)&Psrc[(mt * 16 + m) * 32 + q * 8];
          oacc[mt] = __builtin_amdgcn_mfma_f32_16x16x32_bf16(PA, VB, oacc[mt], 0, 0, 0);
        }
      }
      #pragma unroll
      for (int mt = 0; mt < 4; mt++)
        #pragma unroll
        for (int r = 0; r < 4; r++)
          AOs[(mt * 16 + q * 4 + r) * 136 + wave * 16 + m] = f2bf(oacc[mt][r]);
    }
    __syncthreads();

    // ---- O-proj + residual into Xs ----
    {
      f32x4 ao4[4];
      #pragma unroll
      for (int mt = 0; mt < 4; mt++) ao4[mt] = (f32x4){0,0,0,0};
      gemm_pref(AOs, 136, fo, m, q, ao4);
      float bov = bo[l * 128 + n0 + m];
      #pragma unroll
      for (int mt = 0; mt < 4; mt++)
        #pragma unroll
        for (int r = 0; r < 4; r++)
          Xs[(mt * 16 + q * 4 + r) * 132 + n0 + m] += ao4[mt][r] + bov;
    }
    __syncthreads();

    // ---- LN2 -> Hs ----
    ln128(Xs, Hs, ln2g + l * 128, ln2b + l * 128, lane, wave);
    __syncthreads();

    // ---- FF: 4 chunks; A (Hs) hoisted once; F1 double-buffered ----
    {
      frag8 Ar[4][4];
      #pragma unroll
      for (int mt = 0; mt < 4; mt++)
        #pragma unroll
        for (int kc = 0; kc < 4; kc++)
          Ar[mt][kc] = *(const frag8*)&Hs[(mt * 16 + m) * 136 + kc * 32 + q * 8];
      f32x4 acc2[4];
      #pragma unroll
      for (int mt = 0; mt < 4; mt++) acc2[mt] = (f32x4){0,0,0,0};
      #pragma unroll 1
      for (int c = 0; c < 4; c++) {
        frag8 f2f[4];
        #pragma unroll
        for (int kc = 0; kc < 4; kc++)
          f2f[kc] = *(const frag8*)(f2wb + (n0 + m) * 512 + c * 128 + kc * 32 + q * 8);
        u16* F1c = (c & 1) ? F1b_ : F1a;
        {
          f32x4 a1[4];
          #pragma unroll
          for (int mt = 0; mt < 4; mt++) a1[mt] = (f32x4){0,0,0,0};
          gemm_hoist(Ar, f1f, a1);
          float b1v = f1b[l * 512 + c * 128 + n0 + m];
          #pragma unroll
          for (int mt = 0; mt < 4; mt++)
            #pragma unroll
            for (int r = 0; r < 4; r++)
              F1c[(mt * 16 + q * 4 + r) * 136 + n0 + m] = f2bf(geluf(a1[mt][r] + b1v));
        }
        __syncthreads();
        if (c < 3) {
          #pragma unroll
          for (int kc = 0; kc < 4; kc++)
            f1f[kc] = *(const frag8*)(f1wb + ((c + 1) * 128 + n0 + m) * 128 + kc * 32 + q * 8);
        }
        gemm_pref(F1c, 136, f2f, m, q, acc2);
        // no barrier: next chunk writes the other buffer
      }
      float b2v = f2b[l * 128 + n0 + m];
      #pragma unroll
      for (int mt = 0; mt < 4; mt++)
        #pragma unroll
        for (int r = 0; r < 4; r++)
          Xs[(mt * 16 + q * 4 + r) * 132 + n0 + m] += acc2[mt][r] + b2v;
    }
    __syncthreads();
  }

  for (int i = tid; i < 8192; i += 512) Xg[i] = Xs[(i >> 7) * 132 + (i & 127)];
}

// ============================================================
// k_head1
// ============================================================
__global__ __launch_bounds__(256) void k_head1(const float* __restrict__ X, const float* __restrict__ ew,
                                               const float* __restrict__ eb, const float* __restrict__ g3,
                                               const float* __restrict__ b3, float* __restrict__ G) {
  __shared__ float Xs[2][8192];
  int b = blockIdx.x, ot = blockIdx.y;
  int tid = threadIdx.x;
  {
    const float4* x1 = (const float4*)(X + b * 8192);
    const float4* x2 = (const float4*)(X + (16 + b) * 8192);
    float4* s1 = (float4*)&Xs[0][0];
    float4* s2 = (float4*)&Xs[1][0];
    for (int i = tid; i < 2048; i += 256) { s1[i] = x1[i]; s2[i] = x2[i]; }
  }
  __syncthreads();
  int w = tid & 127, og = tid >> 7;
  int oc0 = ot * 16 + og * 8;
  float a[8] = {};
  for (int ic = 0; ic < 64; ic++) {
    float x1v = Xs[0][ic * 128 + w], x2v = Xs[1][ic * 128 + w];
    #pragma unroll
    for (int j = 0; j < 8; j++) {
      a[j] = fmaf(ew[((oc0 + j) * 64 + ic) * 2 + 0], x1v, a[j]);
      a[j] = fmaf(ew[((oc0 + j) * 64 + ic) * 2 + 1], x2v, a[j]);
    }
  }
  #pragma unroll
  for (int j = 0; j < 8; j++) {
    int oc = oc0 + j;
    float v = (a[j] + eb[oc]) * (g3[oc] * BN_S) + b3[oc];
    G[(b * 64 + oc) * 128 + w] = eluf(v);
  }
}

// ============================================================
// k_head2
// ============================================================
__global__ __launch_bounds__(256) void k_head2(const float* __restrict__ G, const float* __restrict__ cw,
                                               const float* __restrict__ cb, float* __restrict__ out) {
  __shared__ float red[256];
  int b = blockIdx.x, c = blockIdx.y, tid = threadIdx.x;
  const float4* g4 = (const float4*)(G + b * 8192);
  const float4* c4 = (const float4*)(cw + c * 8192);
  float p = 0.f;
  for (int i = tid; i < 2048; i += 256) {
    float4 g = g4[i], w = c4[i];
    p += g.x * w.x + g.y * w.y + g.z * w.z + g.w * w.w;
  }
  red[tid] = p;
  __syncthreads();
  for (int s = 128; s > 0; s >>= 1) {
    if (tid < s) red[tid] += red[tid + s];
    __syncthreads();
  }
  if (tid == 0) out[b * 4 + c] = red[0] + cb[c];
}

// ============================================================
extern "C" void kernel_launch(void* const* d_in, const int* in_sizes, int n_in,
                              void* d_out, int out_size, void* d_ws, size_t ws_size,
                              hipStream_t stream) {
  const float* x    = (const float*)d_in[0];
  const float* tw1  = (const float*)d_in[1];  const float* tb1 = (const float*)d_in[2];
  const float* tw2  = (const float*)d_in[3];  const float* tb2 = (const float*)d_in[4];
  const float* tw3  = (const float*)d_in[5];  const float* tb3 = (const float*)d_in[6];
  const float* tw4  = (const float*)d_in[7];  const float* tb4 = (const float*)d_in[8];
  const float* bn1g = (const float*)d_in[9];  const float* bn1b = (const float*)d_in[10];
  const float* sw   = (const float*)d_in[11]; const float* sb   = (const float*)d_in[12];
  const float* bn2g = (const float*)d_in[13]; const float* bn2b = (const float*)d_in[14];
  const float* ln1g = (const float*)d_in[15]; const float* ln1b = (const float*)d_in[16];
  const float* ln2g = (const float*)d_in[17]; const float* ln2b = (const float*)d_in[18];
  const float* wq   = (const float*)d_in[19]; const float* bq   = (const float*)d_in[20];
  const float* wk   = (const float*)d_in[21]; const float* bk   = (const float*)d_in[22];
  const float* wv   = (const float*)d_in[23]; const float* bv   = (const float*)d_in[24];
  const float* wo   = (const float*)d_in[25]; const float* bo   = (const float*)d_in[26];
  const float* f1w  = (const float*)d_in[27]; const float* f1b  = (const float*)d_in[28];
  const float* f2w  = (const float*)d_in[29]; const float* f2b  = (const float*)d_in[30];
  const float* ew   = (const float*)d_in[31]; const float* eb   = (const float*)d_in[32];
  const float* g3   = (const float*)d_in[33]; const float* b3   = (const float*)d_in[34];
  const float* cw   = (const float*)d_in[35]; const float* cb   = (const float*)d_in[36];

  float* ws      = (float*)d_ws;
  float* tws1    = ws;               // 8320
  float* c1      = ws + 8320;        // 128
  float* biasEff = ws + 8448;        // 128
  u16*   Wb      = (u16*)(ws + 8576);// 532480 bf16 [u][o][kh] (1.04 MB)
  float* z       = ws + 541056;      // 2048000 [b][o][t]; reused as G after pool
  float* X       = ws + 2589056;     // 262144  [2048][128]
  u16*   Wenc    = (u16*)(ws + 3113344); // 786432 bf16 encoder weights (1.5 MB)
  float* G       = z;                // 131072 (z dead after k_pool)

  k_cvt6<<<768, 256, 0, stream>>>(wq, wk, wv, wo, f1w, f2w, Wenc);
  k_tws1<<<33, 256, 0, stream>>>(tw1, tw2, tw3, tw4, tb1, tb2, tb3, tb4, bn1g, bn1b, tws1, c1);
  k_weff<<<128, 256, 0, stream>>>(sw, sb, tws1, c1, Wb, biasEff);
  k_conv<<<dim3(16, 4, 16), 256, 0, stream>>>(x, Wb, biasEff, bn2g, bn2b, z);
  k_pool<<<dim3(16, 8), 256, 0, stream>>>(z, X);

  k_enc<<<32, 512, 0, stream>>>(X, Wenc, ln1g, ln1b, ln2g, ln2b, bq, bk, bv, bo, f1b, f2b);

  k_head1<<<dim3(16, 4), 256, 0, stream>>>(X, ew, eb, g3, b3, G);
  k_head2<<<dim3(16, 4), 256, 0, stream>>>(G, cw, cb, (float*)d_out);
}